// Round 1
// baseline (1721.196 us; speedup 1.0000x reference)
//
#include <hip/hip_runtime.h>

#define N_USERS 100000
#define N_ITEMS 50000
#define N_NODES 150000
#define DIM 32
#define N_EDGES 8000000
#define B_OUT 65536
#define SCAN_T 1024

// ---------------------------------------------------------------------------
// 1. Build x_a = concat(user_emb, item_emb); emb_sum = same.
// ---------------------------------------------------------------------------
__global__ void init_kernel(const float* __restrict__ user_emb,
                            const float* __restrict__ item_emb,
                            float* __restrict__ x_a,
                            float* __restrict__ emb_sum) {
    int i = blockIdx.x * blockDim.x + threadIdx.x;   // float4 index
    const int total = N_NODES * DIM / 4;             // 1,200,000
    if (i >= total) return;
    const int user_f4 = N_USERS * DIM / 4;           // 800,000
    float4 v;
    if (i < user_f4) v = ((const float4*)user_emb)[i];
    else             v = ((const float4*)item_emb)[i - user_f4];
    ((float4*)x_a)[i]     = v;
    ((float4*)emb_sum)[i] = v;
}

// ---------------------------------------------------------------------------
// 2. Histogram of row indices.
// ---------------------------------------------------------------------------
__global__ void hist_kernel(const int* __restrict__ rows, int* __restrict__ counts) {
    int e = blockIdx.x * blockDim.x + threadIdx.x;
    if (e < N_EDGES) atomicAdd(&counts[rows[e]], 1);
}

// ---------------------------------------------------------------------------
// 3. Exclusive scan -> row_ptr[N_NODES+1]; also init cursor = row_ptr.
//    Single workgroup, chunked Hillis-Steele in LDS.
// ---------------------------------------------------------------------------
__global__ void scan_kernel(const int* __restrict__ counts,
                            int* __restrict__ row_ptr,
                            int* __restrict__ cursor) {
    __shared__ int s[SCAN_T];
    const int tid = threadIdx.x;
    int carry = 0;
    const int nchunks = (N_NODES + 1 + SCAN_T - 1) / SCAN_T;  // 147
    for (int ch = 0; ch < nchunks; ++ch) {
        int idx = ch * SCAN_T + tid;
        int v = (idx < N_NODES) ? counts[idx] : 0;
        s[tid] = v;
        __syncthreads();
        #pragma unroll
        for (int off = 1; off < SCAN_T; off <<= 1) {
            int t = (tid >= off) ? s[tid - off] : 0;
            __syncthreads();
            s[tid] += t;
            __syncthreads();
        }
        int incl = s[tid];
        int excl = incl - v;
        if (idx <= N_NODES) {
            row_ptr[idx] = carry + excl;
            if (idx < N_NODES) cursor[idx] = carry + excl;
        }
        int tot = s[SCAN_T - 1];
        __syncthreads();
        carry += tot;
    }
}

// ---------------------------------------------------------------------------
// 4. Scatter edges into CSR order.
// ---------------------------------------------------------------------------
__global__ void scatter_kernel(const int* __restrict__ rows,
                               const int* __restrict__ cols,
                               const float* __restrict__ vals,
                               int* __restrict__ cursor,
                               int* __restrict__ csr_col,
                               float* __restrict__ csr_val) {
    int e = blockIdx.x * blockDim.x + threadIdx.x;
    if (e >= N_EDGES) return;
    int r = rows[e];
    int pos = atomicAdd(&cursor[r], 1);
    csr_col[pos] = cols[e];
    csr_val[pos] = vals[e];
}

// ---------------------------------------------------------------------------
// 5. CSR SpMM: xout[r, :] = sum_e val[e] * xin[col[e], :]
//    One 32-lane half-wave per row; lane = dim. No atomics.
// ---------------------------------------------------------------------------
__global__ void spmm_kernel(const int* __restrict__ row_ptr,
                            const int* __restrict__ csr_col,
                            const float* __restrict__ csr_val,
                            const float* __restrict__ xin,
                            float* __restrict__ xout) {
    int tid = blockIdx.x * blockDim.x + threadIdx.x;
    int row = tid >> 5;
    int d   = tid & 31;
    if (row >= N_NODES) return;
    int s = row_ptr[row];
    int e = row_ptr[row + 1];
    float acc = 0.f;
    int i = s;
    for (; i + 4 <= e; i += 4) {
        int   c0 = csr_col[i],     c1 = csr_col[i + 1];
        int   c2 = csr_col[i + 2], c3 = csr_col[i + 3];
        float v0 = csr_val[i],     v1 = csr_val[i + 1];
        float v2 = csr_val[i + 2], v3 = csr_val[i + 3];
        float x0 = xin[c0 * DIM + d];
        float x1 = xin[c1 * DIM + d];
        float x2 = xin[c2 * DIM + d];
        float x3 = xin[c3 * DIM + d];
        acc += v0 * x0 + v1 * x1 + v2 * x2 + v3 * x3;
    }
    for (; i < e; ++i) acc += csr_val[i] * xin[csr_col[i] * DIM + d];
    xout[row * DIM + d] = acc;
}

// ---------------------------------------------------------------------------
// 6. emb_sum += src
// ---------------------------------------------------------------------------
__global__ void add_kernel(float* __restrict__ dst, const float* __restrict__ src) {
    int i = blockIdx.x * blockDim.x + threadIdx.x;
    const int total = N_NODES * DIM / 4;
    if (i >= total) return;
    float4 a = ((float4*)dst)[i];
    float4 b = ((const float4*)src)[i];
    a.x += b.x; a.y += b.y; a.z += b.z; a.w += b.w;
    ((float4*)dst)[i] = a;
}

// ---------------------------------------------------------------------------
// 7. Readout: light = (emb_sum + last)/4; gamma = <light_u, light_i>;
//    out = gamma*std[u] + mean[u].  Fuses the final emb_sum += last.
// ---------------------------------------------------------------------------
__global__ void final_kernel(const int* __restrict__ users,
                             const int* __restrict__ items,
                             const float* __restrict__ emb_sum,
                             const float* __restrict__ last,
                             const float* __restrict__ means,
                             const float* __restrict__ stds,
                             float* __restrict__ out) {
    int b = blockIdx.x * blockDim.x + threadIdx.x;
    if (b >= B_OUT) return;
    int u  = users[b];
    int it = items[b] + N_USERS;
    const float4* su = (const float4*)(emb_sum + (size_t)u  * DIM);
    const float4* lu = (const float4*)(last    + (size_t)u  * DIM);
    const float4* si = (const float4*)(emb_sum + (size_t)it * DIM);
    const float4* li = (const float4*)(last    + (size_t)it * DIM);
    float gamma = 0.f;
    #pragma unroll
    for (int k = 0; k < DIM / 4; ++k) {
        float4 a = su[k], a2 = lu[k], c = si[k], c2 = li[k];
        float ux = (a.x + a2.x) * 0.25f, uy = (a.y + a2.y) * 0.25f;
        float uz = (a.z + a2.z) * 0.25f, uw = (a.w + a2.w) * 0.25f;
        float ix = (c.x + c2.x) * 0.25f, iy = (c.y + c2.y) * 0.25f;
        float iz = (c.z + c2.z) * 0.25f, iw = (c.w + c2.w) * 0.25f;
        gamma += ux * ix + uy * iy + uz * iz + uw * iw;
    }
    out[b] = gamma * stds[u] + means[u];
}

extern "C" void kernel_launch(void* const* d_in, const int* in_sizes, int n_in,
                              void* d_out, int out_size, void* d_ws, size_t ws_size,
                              hipStream_t stream) {
    const int*   users    = (const int*)d_in[0];
    const int*   items    = (const int*)d_in[1];
    const int*   rows     = (const int*)d_in[2];
    const int*   cols     = (const int*)d_in[3];
    const float* vals     = (const float*)d_in[4];
    const float* user_emb = (const float*)d_in[5];
    const float* item_emb = (const float*)d_in[6];
    const float* means    = (const float*)d_in[7];
    const float* stds     = (const float*)d_in[8];
    float* out = (float*)d_out;

    // Workspace carve-up (256B aligned slices).
    char* w = (char*)d_ws;
    size_t off = 0;
    auto alloc = [&](size_t bytes) -> void* {
        void* p = w + off;
        off = (off + bytes + 255) & ~(size_t)255;
        return p;
    };
    float* x_a     = (float*)alloc((size_t)N_NODES * DIM * sizeof(float));
    float* x_b     = (float*)alloc((size_t)N_NODES * DIM * sizeof(float));
    float* emb_sum = (float*)alloc((size_t)N_NODES * DIM * sizeof(float));
    int*   counts  = (int*)  alloc((size_t)N_NODES * sizeof(int));
    int*   row_ptr = (int*)  alloc((size_t)(N_NODES + 1) * sizeof(int));
    int*   cursor  = (int*)  alloc((size_t)N_NODES * sizeof(int));
    int*   csr_col = (int*)  alloc((size_t)N_EDGES * sizeof(int));
    float* csr_val = (float*)alloc((size_t)N_EDGES * sizeof(float));
    (void)ws_size;

    const int T = 256;
    const int g_init  = (N_NODES * DIM / 4 + T - 1) / T;   // 4688
    const int g_edges = (N_EDGES + T - 1) / T;             // 31250
    const int g_spmm  = (N_NODES * DIM + T - 1) / T;       // 18750 (8 rows/block)
    const int g_final = (B_OUT + T - 1) / T;               // 256

    // CSR build
    hipMemsetAsync(counts, 0, (size_t)N_NODES * sizeof(int), stream);
    hist_kernel<<<g_edges, T, 0, stream>>>(rows, counts);
    scan_kernel<<<1, SCAN_T, 0, stream>>>(counts, row_ptr, cursor);
    scatter_kernel<<<g_edges, T, 0, stream>>>(rows, cols, vals, cursor, csr_col, csr_val);

    // x_a = all_emb; emb_sum = all_emb
    init_kernel<<<g_init, T, 0, stream>>>(user_emb, item_emb, x_a, emb_sum);

    // Layer 1: x_b = A x_a ; emb_sum += x_b
    spmm_kernel<<<g_spmm, T, 0, stream>>>(row_ptr, csr_col, csr_val, x_a, x_b);
    add_kernel<<<g_init, T, 0, stream>>>(emb_sum, x_b);
    // Layer 2: x_a = A x_b ; emb_sum += x_a
    spmm_kernel<<<g_spmm, T, 0, stream>>>(row_ptr, csr_col, csr_val, x_b, x_a);
    add_kernel<<<g_init, T, 0, stream>>>(emb_sum, x_a);
    // Layer 3: x_b = A x_a ; final add fused into readout
    spmm_kernel<<<g_spmm, T, 0, stream>>>(row_ptr, csr_col, csr_val, x_a, x_b);

    final_kernel<<<g_final, T, 0, stream>>>(users, items, emb_sum, x_b, means, stds, out);
}

// Round 2
// 1411.700 us; speedup vs baseline: 1.2192x; 1.2192x over previous
//
#include <hip/hip_runtime.h>

#define N_USERS 100000
#define N_ITEMS 50000
#define N_NODES 150000
#define DIM 32
#define N_EDGES 8000000
#define B_OUT 65536

// ---------------------------------------------------------------------------
// 1. x_a = concat(user_emb, item_emb); emb_sum = same.
// ---------------------------------------------------------------------------
__global__ void init_kernel(const float* __restrict__ user_emb,
                            const float* __restrict__ item_emb,
                            float* __restrict__ x_a,
                            float* __restrict__ emb_sum) {
    int i = blockIdx.x * blockDim.x + threadIdx.x;   // float4 index
    const int total = N_NODES * DIM / 4;             // 1,200,000
    if (i >= total) return;
    const int user_f4 = N_USERS * DIM / 4;           // 800,000
    float4 v;
    if (i < user_f4) v = ((const float4*)user_emb)[i];
    else             v = ((const float4*)item_emb)[i - user_f4];
    ((float4*)x_a)[i]     = v;
    ((float4*)emb_sum)[i] = v;
}

// ---------------------------------------------------------------------------
// 2. Histogram of row indices.
// ---------------------------------------------------------------------------
__global__ void hist_kernel(const int* __restrict__ rows, int* __restrict__ counts) {
    int e = blockIdx.x * blockDim.x + threadIdx.x;
    if (e < N_EDGES) atomicAdd(&counts[rows[e]], 1);
}

// ---------------------------------------------------------------------------
// 3. Two-level exclusive scan of counts -> row_ptr / cursor.
//    s1: per-block sums.  s2: scan of 586 block sums (1 block).
//    s3: per-block scan + carry, writes row_ptr[idx] and cursor[idx];
//        last element also writes row_ptr[N_NODES].
// ---------------------------------------------------------------------------
#define SCAN_B 256
#define N_SBLK ((N_NODES + SCAN_B - 1) / SCAN_B)   // 586

__global__ void scan1_kernel(const int* __restrict__ counts, int* __restrict__ bsum) {
    __shared__ int s[SCAN_B];
    int idx = blockIdx.x * SCAN_B + threadIdx.x;
    int v = (idx < N_NODES) ? counts[idx] : 0;
    s[threadIdx.x] = v;
    __syncthreads();
    for (int off = SCAN_B / 2; off > 0; off >>= 1) {
        if (threadIdx.x < off) s[threadIdx.x] += s[threadIdx.x + off];
        __syncthreads();
    }
    if (threadIdx.x == 0) bsum[blockIdx.x] = s[0];
}

__global__ void scan2_kernel(int* __restrict__ bsum, int* __restrict__ boff) {
    __shared__ int s[1024];
    int tid = threadIdx.x;
    int v = (tid < N_SBLK) ? bsum[tid] : 0;
    s[tid] = v;
    __syncthreads();
    for (int off = 1; off < 1024; off <<= 1) {
        int t = (tid >= off) ? s[tid - off] : 0;
        __syncthreads();
        s[tid] += t;
        __syncthreads();
    }
    if (tid < N_SBLK) boff[tid] = s[tid] - v;   // exclusive
}

__global__ void scan3_kernel(const int* __restrict__ counts,
                             const int* __restrict__ boff,
                             int* __restrict__ row_ptr,
                             int* __restrict__ cursor) {
    __shared__ int s[SCAN_B];
    int idx = blockIdx.x * SCAN_B + threadIdx.x;
    int tid = threadIdx.x;
    int v = (idx < N_NODES) ? counts[idx] : 0;
    s[tid] = v;
    __syncthreads();
    for (int off = 1; off < SCAN_B; off <<= 1) {
        int t = (tid >= off) ? s[tid - off] : 0;
        __syncthreads();
        s[tid] += t;
        __syncthreads();
    }
    if (idx < N_NODES) {
        int base = boff[blockIdx.x];
        int excl = base + s[tid] - v;
        row_ptr[idx] = excl;
        cursor[idx]  = excl;
        if (idx == N_NODES - 1) row_ptr[N_NODES] = base + s[tid];
    }
}

// ---------------------------------------------------------------------------
// 4. Scatter edges into CSR order — single 8B (col,val) write per edge.
// ---------------------------------------------------------------------------
__global__ void scatter_kernel(const int* __restrict__ rows,
                               const int* __restrict__ cols,
                               const float* __restrict__ vals,
                               int* __restrict__ cursor,
                               int2* __restrict__ csr_ev) {
    int e = blockIdx.x * blockDim.x + threadIdx.x;
    if (e >= N_EDGES) return;
    int r = rows[e];
    int pos = atomicAdd(&cursor[r], 1);
    int2 ev;
    ev.x = cols[e];
    ev.y = __float_as_int(vals[e]);
    csr_ev[pos] = ev;
}

// ---------------------------------------------------------------------------
// 5. CSR SpMM + fused emb_sum update:
//    xout[r,:] = sum val * xin[col,:];  emb_sum[r,:] += xout[r,:]
//    One 32-lane half-wave per row; lane = dim. No atomics.
// ---------------------------------------------------------------------------
__global__ void spmm_kernel(const int* __restrict__ row_ptr,
                            const int2* __restrict__ csr_ev,
                            const float* __restrict__ xin,
                            float* __restrict__ xout,
                            float* __restrict__ emb_sum) {
    int tid = blockIdx.x * blockDim.x + threadIdx.x;
    int row = tid >> 5;
    int d   = tid & 31;
    if (row >= N_NODES) return;
    int s = row_ptr[row];
    int e = row_ptr[row + 1];
    float acc = 0.f;
    int i = s;
    for (; i + 4 <= e; i += 4) {
        int2 e0 = csr_ev[i],     e1 = csr_ev[i + 1];
        int2 e2 = csr_ev[i + 2], e3 = csr_ev[i + 3];
        float x0 = xin[e0.x * DIM + d];
        float x1 = xin[e1.x * DIM + d];
        float x2 = xin[e2.x * DIM + d];
        float x3 = xin[e3.x * DIM + d];
        acc += __int_as_float(e0.y) * x0 + __int_as_float(e1.y) * x1
             + __int_as_float(e2.y) * x2 + __int_as_float(e3.y) * x3;
    }
    for (; i < e; ++i) {
        int2 ev = csr_ev[i];
        acc += __int_as_float(ev.y) * xin[ev.x * DIM + d];
    }
    int o = row * DIM + d;
    xout[o] = acc;
    emb_sum[o] += acc;
}

// ---------------------------------------------------------------------------
// 6. Readout: light = emb_sum/4; gamma = <light_u, light_i>;
//    out = gamma*std[u] + mean[u].
// ---------------------------------------------------------------------------
__global__ void final_kernel(const int* __restrict__ users,
                             const int* __restrict__ items,
                             const float* __restrict__ emb_sum,
                             const float* __restrict__ means,
                             const float* __restrict__ stds,
                             float* __restrict__ out) {
    int b = blockIdx.x * blockDim.x + threadIdx.x;
    if (b >= B_OUT) return;
    int u  = users[b];
    int it = items[b] + N_USERS;
    const float4* su = (const float4*)(emb_sum + (size_t)u  * DIM);
    const float4* si = (const float4*)(emb_sum + (size_t)it * DIM);
    float gamma = 0.f;
    #pragma unroll
    for (int k = 0; k < DIM / 4; ++k) {
        float4 a = su[k], c = si[k];
        gamma += (a.x * 0.25f) * (c.x * 0.25f) + (a.y * 0.25f) * (c.y * 0.25f)
               + (a.z * 0.25f) * (c.z * 0.25f) + (a.w * 0.25f) * (c.w * 0.25f);
    }
    out[b] = gamma * stds[u] + means[u];
}

extern "C" void kernel_launch(void* const* d_in, const int* in_sizes, int n_in,
                              void* d_out, int out_size, void* d_ws, size_t ws_size,
                              hipStream_t stream) {
    const int*   users    = (const int*)d_in[0];
    const int*   items    = (const int*)d_in[1];
    const int*   rows     = (const int*)d_in[2];
    const int*   cols     = (const int*)d_in[3];
    const float* vals     = (const float*)d_in[4];
    const float* user_emb = (const float*)d_in[5];
    const float* item_emb = (const float*)d_in[6];
    const float* means    = (const float*)d_in[7];
    const float* stds     = (const float*)d_in[8];
    float* out = (float*)d_out;

    char* w = (char*)d_ws;
    size_t off = 0;
    auto alloc = [&](size_t bytes) -> void* {
        void* p = w + off;
        off = (off + bytes + 255) & ~(size_t)255;
        return p;
    };
    float* x_a     = (float*)alloc((size_t)N_NODES * DIM * sizeof(float));
    float* x_b     = (float*)alloc((size_t)N_NODES * DIM * sizeof(float));
    float* emb_sum = (float*)alloc((size_t)N_NODES * DIM * sizeof(float));
    int*   counts  = (int*)  alloc((size_t)N_NODES * sizeof(int));
    int*   row_ptr = (int*)  alloc((size_t)(N_NODES + 1) * sizeof(int));
    int*   cursor  = (int*)  alloc((size_t)N_NODES * sizeof(int));
    int*   bsum    = (int*)  alloc((size_t)N_SBLK * sizeof(int));
    int*   boff    = (int*)  alloc((size_t)N_SBLK * sizeof(int));
    int2*  csr_ev  = (int2*) alloc((size_t)N_EDGES * sizeof(int2));
    (void)ws_size;

    const int T = 256;
    const int g_init  = (N_NODES * DIM / 4 + T - 1) / T;   // 4688
    const int g_edges = (N_EDGES + T - 1) / T;             // 31250
    const int g_spmm  = (N_NODES * DIM + T - 1) / T;       // 18750 (8 rows/block)
    const int g_final = (B_OUT + T - 1) / T;               // 256

    // CSR build
    hipMemsetAsync(counts, 0, (size_t)N_NODES * sizeof(int), stream);
    hist_kernel<<<g_edges, T, 0, stream>>>(rows, counts);
    scan1_kernel<<<N_SBLK, SCAN_B, 0, stream>>>(counts, bsum);
    scan2_kernel<<<1, 1024, 0, stream>>>(bsum, boff);
    scan3_kernel<<<N_SBLK, SCAN_B, 0, stream>>>(counts, boff, row_ptr, cursor);
    scatter_kernel<<<g_edges, T, 0, stream>>>(rows, cols, vals, cursor, csr_ev);

    // x_a = all_emb; emb_sum = all_emb
    init_kernel<<<g_init, T, 0, stream>>>(user_emb, item_emb, x_a, emb_sum);

    // 3 SpMM layers, emb_sum fused
    spmm_kernel<<<g_spmm, T, 0, stream>>>(row_ptr, csr_ev, x_a, x_b, emb_sum);
    spmm_kernel<<<g_spmm, T, 0, stream>>>(row_ptr, csr_ev, x_b, x_a, emb_sum);
    spmm_kernel<<<g_spmm, T, 0, stream>>>(row_ptr, csr_ev, x_a, x_b, emb_sum);

    final_kernel<<<g_final, T, 0, stream>>>(users, items, emb_sum, means, stds, out);
}

// Round 3
// 970.022 us; speedup vs baseline: 1.7744x; 1.4553x over previous
//
#include <hip/hip_runtime.h>

#define N_USERS 100000
#define N_ITEMS 50000
#define N_NODES 150000
#define DIM 32
#define N_EDGES 8000000
#define B_OUT 65536

#define NB 1024            // row buckets
#define RPB 147            // rows per bucket (1024*147 = 150528 >= 150000)
#define PART_T 256
#define EPT 32             // edges per thread in partition
#define CH (PART_T * EPT)  // 8192 edges per block-chunk
#define N_PBLK ((N_EDGES + CH - 1) / CH)   // 977

// ---------------------------------------------------------------------------
// x_a = concat(user_emb, item_emb); emb_sum = same.
// ---------------------------------------------------------------------------
__global__ void init_kernel(const float* __restrict__ user_emb,
                            const float* __restrict__ item_emb,
                            float* __restrict__ x_a,
                            float* __restrict__ emb_sum) {
    int i = blockIdx.x * blockDim.x + threadIdx.x;   // float4 index
    const int total = N_NODES * DIM / 4;
    if (i >= total) return;
    const int user_f4 = N_USERS * DIM / 4;
    float4 v;
    if (i < user_f4) v = ((const float4*)user_emb)[i];
    else             v = ((const float4*)item_emb)[i - user_f4];
    ((float4*)x_a)[i]     = v;
    ((float4*)emb_sum)[i] = v;
}

// ---------------------------------------------------------------------------
// Histogram of row indices.
// ---------------------------------------------------------------------------
__global__ void hist_kernel(const int* __restrict__ rows, int* __restrict__ counts) {
    int e = blockIdx.x * blockDim.x + threadIdx.x;
    if (e < N_EDGES) atomicAdd(&counts[rows[e]], 1);
}

// ---------------------------------------------------------------------------
// Two-level exclusive scan of counts -> row_ptr.
// ---------------------------------------------------------------------------
#define SCAN_B 256
#define N_SBLK ((N_NODES + SCAN_B - 1) / SCAN_B)   // 586

__global__ void scan1_kernel(const int* __restrict__ counts, int* __restrict__ bsum) {
    __shared__ int s[SCAN_B];
    int idx = blockIdx.x * SCAN_B + threadIdx.x;
    int v = (idx < N_NODES) ? counts[idx] : 0;
    s[threadIdx.x] = v;
    __syncthreads();
    for (int off = SCAN_B / 2; off > 0; off >>= 1) {
        if (threadIdx.x < off) s[threadIdx.x] += s[threadIdx.x + off];
        __syncthreads();
    }
    if (threadIdx.x == 0) bsum[blockIdx.x] = s[0];
}

__global__ void scan2_kernel(int* __restrict__ bsum, int* __restrict__ boff) {
    __shared__ int s[1024];
    int tid = threadIdx.x;
    int v = (tid < N_SBLK) ? bsum[tid] : 0;
    s[tid] = v;
    __syncthreads();
    for (int off = 1; off < 1024; off <<= 1) {
        int t = (tid >= off) ? s[tid - off] : 0;
        __syncthreads();
        s[tid] += t;
        __syncthreads();
    }
    if (tid < N_SBLK) boff[tid] = s[tid] - v;   // exclusive
}

__global__ void scan3_kernel(const int* __restrict__ counts,
                             const int* __restrict__ boff,
                             int* __restrict__ row_ptr) {
    __shared__ int s[SCAN_B];
    int idx = blockIdx.x * SCAN_B + threadIdx.x;
    int tid = threadIdx.x;
    int v = (idx < N_NODES) ? counts[idx] : 0;
    s[tid] = v;
    __syncthreads();
    for (int off = 1; off < SCAN_B; off <<= 1) {
        int t = (tid >= off) ? s[tid - off] : 0;
        __syncthreads();
        s[tid] += t;
        __syncthreads();
    }
    if (idx < N_NODES) {
        int base = boff[blockIdx.x];
        row_ptr[idx] = base + s[tid] - v;
        if (idx == N_NODES - 1) row_ptr[N_NODES] = base + s[tid];
    }
}

// ---------------------------------------------------------------------------
// Bucket sizes from row_ptr; 64B-padded exclusive scan -> bucket bases.
// Single block of NB threads. gcur = running cursor for partition.
// ---------------------------------------------------------------------------
__global__ void bucket_scan_kernel(const int* __restrict__ row_ptr,
                                   int* __restrict__ bbase,
                                   int* __restrict__ bcnt,
                                   int* __restrict__ gcur) {
    __shared__ int s[NB];
    int b = threadIdx.x;
    int r0 = b * RPB; if (r0 > N_NODES) r0 = N_NODES;
    int r1 = r0 + RPB; if (r1 > N_NODES) r1 = N_NODES;
    int c = row_ptr[r1] - row_ptr[r0];
    int p = (c + 7) & ~7;          // pad to 8 edges (64B of int2)
    s[b] = p;
    __syncthreads();
    for (int off = 1; off < NB; off <<= 1) {
        int t = (b >= off) ? s[b - off] : 0;
        __syncthreads();
        s[b] += t;
        __syncthreads();
    }
    int excl = s[b] - p;
    bcnt[b]  = c;
    bbase[b] = excl;
    gcur[b]  = excl;
}

// ---------------------------------------------------------------------------
// Partition: chunked two-pass multisplit into NB row-buckets.
// Payload: int2{ (row_local<<18)|col , val_bits }. Writes land as ~64B runs.
// ---------------------------------------------------------------------------
__global__ void part_kernel(const int* __restrict__ rows,
                            const int* __restrict__ cols,
                            const float* __restrict__ vals,
                            int* __restrict__ gcur,
                            int2* __restrict__ bucket_ev) {
    __shared__ int cnt[NB];
    __shared__ int rk[NB];
    __shared__ int base[NB];
    const int tid = threadIdx.x;
    const int e0  = blockIdx.x * CH;

    for (int i = tid; i < NB; i += PART_T) { cnt[i] = 0; rk[i] = 0; }
    __syncthreads();

    int myrow[EPT];
    #pragma unroll
    for (int j = 0; j < EPT; ++j) {
        int e = e0 + j * PART_T + tid;
        int r = (e < N_EDGES) ? rows[e] : -1;
        myrow[j] = r;
        if (r >= 0) atomicAdd(&cnt[(unsigned)r / RPB], 1);
    }
    __syncthreads();
    for (int b = tid; b < NB; b += PART_T) {
        int c = cnt[b];
        if (c > 0) base[b] = atomicAdd(&gcur[b], c);
    }
    __syncthreads();
    #pragma unroll
    for (int j = 0; j < EPT; ++j) {
        int r = myrow[j];
        if (r < 0) continue;
        int e = e0 + j * PART_T + tid;
        unsigned b = (unsigned)r / RPB;
        int k = atomicAdd(&rk[b], 1);
        int2 ev;
        ev.x = (int)(((unsigned)(r - (int)b * RPB) << 18) | (unsigned)cols[e]);
        ev.y = __float_as_int(vals[e]);
        bucket_ev[base[b] + k] = ev;
    }
}

// ---------------------------------------------------------------------------
// Mini-scatter: one block per bucket. LDS row-cursors -> exact CSR.
// All writes confined to the bucket's CSR span (~63KB) -> full-line fills.
// ---------------------------------------------------------------------------
__global__ void mini_scatter_kernel(const int2* __restrict__ bucket_ev,
                                    const int* __restrict__ bbase,
                                    const int* __restrict__ bcnt,
                                    const int* __restrict__ row_ptr,
                                    int2* __restrict__ csr_ev) {
    __shared__ int cur[RPB + 1];
    const int b   = blockIdx.x;
    const int tid = threadIdx.x;
    const int row0 = b * RPB;
    for (int i = tid; i < RPB; i += blockDim.x) {
        int r = row0 + i;
        cur[i] = (r < N_NODES) ? row_ptr[r] : 0;
    }
    __syncthreads();
    const int cnt  = bcnt[b];
    const int base = bbase[b];
    for (int i = tid; i < cnt; i += blockDim.x) {
        int2 ev = bucket_ev[base + i];
        unsigned key = (unsigned)ev.x;
        int rl  = (int)(key >> 18);
        int col = (int)(key & 0x3FFFFu);
        int pos = atomicAdd(&cur[rl], 1);
        int2 o; o.x = col; o.y = ev.y;
        csr_ev[pos] = o;
    }
}

// ---------------------------------------------------------------------------
// CSR SpMM + fused emb_sum update. Half-wave per row, lane = dim.
// ---------------------------------------------------------------------------
__global__ void spmm_kernel(const int* __restrict__ row_ptr,
                            const int2* __restrict__ csr_ev,
                            const float* __restrict__ xin,
                            float* __restrict__ xout,
                            float* __restrict__ emb_sum) {
    int tid = blockIdx.x * blockDim.x + threadIdx.x;
    int row = tid >> 5;
    int d   = tid & 31;
    if (row >= N_NODES) return;
    int s = row_ptr[row];
    int e = row_ptr[row + 1];
    float acc = 0.f;
    int i = s;
    for (; i + 4 <= e; i += 4) {
        int2 e0 = csr_ev[i],     e1 = csr_ev[i + 1];
        int2 e2 = csr_ev[i + 2], e3 = csr_ev[i + 3];
        float x0 = xin[e0.x * DIM + d];
        float x1 = xin[e1.x * DIM + d];
        float x2 = xin[e2.x * DIM + d];
        float x3 = xin[e3.x * DIM + d];
        acc += __int_as_float(e0.y) * x0 + __int_as_float(e1.y) * x1
             + __int_as_float(e2.y) * x2 + __int_as_float(e3.y) * x3;
    }
    for (; i < e; ++i) {
        int2 ev = csr_ev[i];
        acc += __int_as_float(ev.y) * xin[ev.x * DIM + d];
    }
    int o = row * DIM + d;
    xout[o] = acc;
    emb_sum[o] += acc;
}

// ---------------------------------------------------------------------------
// Readout.
// ---------------------------------------------------------------------------
__global__ void final_kernel(const int* __restrict__ users,
                             const int* __restrict__ items,
                             const float* __restrict__ emb_sum,
                             const float* __restrict__ means,
                             const float* __restrict__ stds,
                             float* __restrict__ out) {
    int b = blockIdx.x * blockDim.x + threadIdx.x;
    if (b >= B_OUT) return;
    int u  = users[b];
    int it = items[b] + N_USERS;
    const float4* su = (const float4*)(emb_sum + (size_t)u  * DIM);
    const float4* si = (const float4*)(emb_sum + (size_t)it * DIM);
    float gamma = 0.f;
    #pragma unroll
    for (int k = 0; k < DIM / 4; ++k) {
        float4 a = su[k], c = si[k];
        gamma += (a.x * 0.25f) * (c.x * 0.25f) + (a.y * 0.25f) * (c.y * 0.25f)
               + (a.z * 0.25f) * (c.z * 0.25f) + (a.w * 0.25f) * (c.w * 0.25f);
    }
    out[b] = gamma * stds[u] + means[u];
}

extern "C" void kernel_launch(void* const* d_in, const int* in_sizes, int n_in,
                              void* d_out, int out_size, void* d_ws, size_t ws_size,
                              hipStream_t stream) {
    const int*   users    = (const int*)d_in[0];
    const int*   items    = (const int*)d_in[1];
    const int*   rows     = (const int*)d_in[2];
    const int*   cols     = (const int*)d_in[3];
    const float* vals     = (const float*)d_in[4];
    const float* user_emb = (const float*)d_in[5];
    const float* item_emb = (const float*)d_in[6];
    const float* means    = (const float*)d_in[7];
    const float* stds     = (const float*)d_in[8];
    float* out = (float*)d_out;

    char* w = (char*)d_ws;
    size_t off = 0;
    auto alloc = [&](size_t bytes) -> void* {
        void* p = w + off;
        off = (off + bytes + 255) & ~(size_t)255;
        return p;
    };
    // Region A: bucket_ev (live: part -> mini_scatter) aliases
    //           {x_a, x_b, emb_sum, counts, bsum, boff} (live: init -> end).
    const size_t BEV_EDGES = (size_t)N_EDGES + NB * 8;   // padded
    size_t regionA = ((size_t)BEV_EDGES * sizeof(int2) + 255) & ~(size_t)255;
    char* a0 = (char*)alloc(regionA);
    int2* bucket_ev = (int2*)a0;
    size_t aoff = 0;
    auto allocA = [&](size_t bytes) -> void* {
        void* p = a0 + aoff;
        aoff = (aoff + bytes + 255) & ~(size_t)255;
        return p;
    };
    float* x_a     = (float*)allocA((size_t)N_NODES * DIM * sizeof(float));
    float* x_b     = (float*)allocA((size_t)N_NODES * DIM * sizeof(float));
    float* emb_sum = (float*)allocA((size_t)N_NODES * DIM * sizeof(float));
    int*   counts  = (int*)  allocA((size_t)N_NODES * sizeof(int));
    int*   bsum    = (int*)  allocA((size_t)N_SBLK * sizeof(int));
    int*   boff    = (int*)  allocA((size_t)N_SBLK * sizeof(int));
    // (aoff ~58.3MB <= regionA ~64.9MB)

    int*   row_ptr = (int*)  alloc((size_t)(N_NODES + 1) * sizeof(int));
    int*   bbase   = (int*)  alloc((size_t)NB * sizeof(int));
    int*   bcnt    = (int*)  alloc((size_t)NB * sizeof(int));
    int*   gcur    = (int*)  alloc((size_t)NB * sizeof(int));
    int2*  csr_ev  = (int2*) alloc((size_t)N_EDGES * sizeof(int2));
    (void)ws_size;

    const int T = 256;
    const int g_init  = (N_NODES * DIM / 4 + T - 1) / T;
    const int g_edges = (N_EDGES + T - 1) / T;
    const int g_spmm  = (N_NODES * DIM + T - 1) / T;
    const int g_final = (B_OUT + T - 1) / T;

    // --- CSR build ---
    hipMemsetAsync(counts, 0, (size_t)N_NODES * sizeof(int), stream);
    hist_kernel<<<g_edges, T, 0, stream>>>(rows, counts);
    scan1_kernel<<<N_SBLK, SCAN_B, 0, stream>>>(counts, bsum);
    scan2_kernel<<<1, 1024, 0, stream>>>(bsum, boff);
    scan3_kernel<<<N_SBLK, SCAN_B, 0, stream>>>(counts, boff, row_ptr);
    bucket_scan_kernel<<<1, NB, 0, stream>>>(row_ptr, bbase, bcnt, gcur);
    part_kernel<<<N_PBLK, PART_T, 0, stream>>>(rows, cols, vals, gcur, bucket_ev);
    mini_scatter_kernel<<<NB, T, 0, stream>>>(bucket_ev, bbase, bcnt, row_ptr, csr_ev);

    // --- dense pipeline (bucket_ev dead from here; region reused) ---
    init_kernel<<<g_init, T, 0, stream>>>(user_emb, item_emb, x_a, emb_sum);
    spmm_kernel<<<g_spmm, T, 0, stream>>>(row_ptr, csr_ev, x_a, x_b, emb_sum);
    spmm_kernel<<<g_spmm, T, 0, stream>>>(row_ptr, csr_ev, x_b, x_a, emb_sum);
    spmm_kernel<<<g_spmm, T, 0, stream>>>(row_ptr, csr_ev, x_a, x_b, emb_sum);

    final_kernel<<<g_final, T, 0, stream>>>(users, items, emb_sum, means, stds, out);
}

// Round 4
// 714.967 us; speedup vs baseline: 2.4074x; 1.3567x over previous
//
#include <hip/hip_runtime.h>

#define N_USERS 100000
#define N_ITEMS 50000
#define N_NODES 150000
#define DIM 32
#define N_EDGES 8000000
#define B_OUT 65536

#define NB 1024            // row buckets
#define RPB 147            // rows per bucket (1024*147 = 150528 >= 150000)
#define PART_T 256
#define EPT 32             // edges per thread in partition/count
#define CH (PART_T * EPT)  // 8192 edges per block-chunk
#define N_PBLK ((N_EDGES + CH - 1) / CH)   // 977

// ---------------------------------------------------------------------------
// x_a = concat(user_emb, item_emb); emb_sum = same.
// ---------------------------------------------------------------------------
__global__ void init_kernel(const float* __restrict__ user_emb,
                            const float* __restrict__ item_emb,
                            float* __restrict__ x_a,
                            float* __restrict__ emb_sum) {
    int i = blockIdx.x * blockDim.x + threadIdx.x;   // float4 index
    const int total = N_NODES * DIM / 4;
    if (i >= total) return;
    const int user_f4 = N_USERS * DIM / 4;
    float4 v;
    if (i < user_f4) v = ((const float4*)user_emb)[i];
    else             v = ((const float4*)item_emb)[i - user_f4];
    ((float4*)x_a)[i]     = v;
    ((float4*)emb_sum)[i] = v;
}

// ---------------------------------------------------------------------------
// 1. Per-chunk bucket histogram (LDS atomics only), coalesced matrix write.
//    cnt[blk][b] = #edges of chunk blk landing in bucket b.
// ---------------------------------------------------------------------------
__global__ void count_kernel(const int* __restrict__ rows, int* __restrict__ cnt) {
    __shared__ int hist[NB];
    const int tid = threadIdx.x;
    const int e0  = blockIdx.x * CH;
    for (int i = tid; i < NB; i += PART_T) hist[i] = 0;
    __syncthreads();
    #pragma unroll
    for (int j = 0; j < EPT; ++j) {
        int e = e0 + j * PART_T + tid;
        if (e < N_EDGES) atomicAdd(&hist[(unsigned)rows[e] / RPB], 1);
    }
    __syncthreads();
    for (int i = tid; i < NB; i += PART_T)
        cnt[(size_t)blockIdx.x * NB + i] = hist[i];
}

// ---------------------------------------------------------------------------
// 2. Column-reduce the count matrix -> total[b]. 64 blocks x 16 buckets each.
// ---------------------------------------------------------------------------
__global__ void reduce_kernel(const int* __restrict__ cnt, int* __restrict__ total) {
    __shared__ int s[256];
    const int t    = threadIdx.x;
    const int bsel = blockIdx.x * 16 + (t & 15);
    int partial = 0;
    for (int blk = (t >> 4); blk < N_PBLK; blk += 16)
        partial += cnt[(size_t)blk * NB + bsel];
    s[t] = partial;
    __syncthreads();
    for (int off = 128; off >= 16; off >>= 1) {
        if (t < off) s[t] += s[t + off];
        __syncthreads();
    }
    if (t < 16) total[blockIdx.x * 16 + t] = s[t];
}

// ---------------------------------------------------------------------------
// 3. Scan bucket totals: padded -> bbase (+gcur), exact -> bcsr.
//    Also writes row_ptr[N_NODES] = N_EDGES.
// ---------------------------------------------------------------------------
__global__ void scan_buckets_kernel(const int* __restrict__ total,
                                    int* __restrict__ bbase,
                                    int* __restrict__ gcur,
                                    int* __restrict__ bcsr,
                                    int* __restrict__ row_ptr) {
    __shared__ int sp[NB];
    __shared__ int se[NB];
    const int b = threadIdx.x;
    int c = total[b];
    int p = (c + 7) & ~7;          // pad to 8 edges (64B of int2)
    sp[b] = p;
    se[b] = c;
    __syncthreads();
    for (int off = 1; off < NB; off <<= 1) {
        int tp = (b >= off) ? sp[b - off] : 0;
        int te = (b >= off) ? se[b - off] : 0;
        __syncthreads();
        sp[b] += tp;
        se[b] += te;
        __syncthreads();
    }
    bbase[b] = sp[b] - p;
    gcur[b]  = sp[b] - p;
    bcsr[b]  = se[b] - c;
    if (b == 0) row_ptr[N_NODES] = N_EDGES;
}

// ---------------------------------------------------------------------------
// 4. Partition: chunked two-pass multisplit into NB row-buckets.
//    Payload: int2{ (row_local<<18)|col , val_bits }. ~64B write runs.
// ---------------------------------------------------------------------------
__global__ void part_kernel(const int* __restrict__ rows,
                            const int* __restrict__ cols,
                            const float* __restrict__ vals,
                            int* __restrict__ gcur,
                            int2* __restrict__ bucket_ev) {
    __shared__ int cnt[NB];
    __shared__ int rk[NB];
    __shared__ int base[NB];
    const int tid = threadIdx.x;
    const int e0  = blockIdx.x * CH;

    for (int i = tid; i < NB; i += PART_T) { cnt[i] = 0; rk[i] = 0; }
    __syncthreads();

    int myrow[EPT];
    #pragma unroll
    for (int j = 0; j < EPT; ++j) {
        int e = e0 + j * PART_T + tid;
        int r = (e < N_EDGES) ? rows[e] : -1;
        myrow[j] = r;
        if (r >= 0) atomicAdd(&cnt[(unsigned)r / RPB], 1);
    }
    __syncthreads();
    for (int b = tid; b < NB; b += PART_T) {
        int c = cnt[b];
        if (c > 0) base[b] = atomicAdd(&gcur[b], c);
    }
    __syncthreads();
    #pragma unroll
    for (int j = 0; j < EPT; ++j) {
        int r = myrow[j];
        if (r < 0) continue;
        int e = e0 + j * PART_T + tid;
        unsigned b = (unsigned)r / RPB;
        int k = atomicAdd(&rk[b], 1);
        int2 ev;
        ev.x = (int)(((unsigned)(r - (int)b * RPB) << 18) | (unsigned)cols[e]);
        ev.y = __float_as_int(vals[e]);
        bucket_ev[base[b] + k] = ev;
    }
}

// ---------------------------------------------------------------------------
// 5. Mini-scatter: one block per bucket. Builds row_ptr for its 147 rows
//    (LDS hist + scan + bcsr offset), then LDS-cursor scatter -> exact CSR.
// ---------------------------------------------------------------------------
__global__ void mini_scatter_kernel(const int2* __restrict__ bucket_ev,
                                    const int* __restrict__ bbase,
                                    const int* __restrict__ total,
                                    const int* __restrict__ bcsr,
                                    int* __restrict__ row_ptr,
                                    int2* __restrict__ csr_ev) {
    __shared__ int cnt_r[RPB];
    __shared__ int s[256];
    __shared__ int cur[RPB];
    const int b    = blockIdx.x;
    const int tid  = threadIdx.x;
    const int row0 = b * RPB;
    const int cnt  = total[b];
    const int base = bbase[b];
    const int cb   = bcsr[b];

    if (tid < RPB) cnt_r[tid] = 0;
    __syncthreads();
    for (int i = tid; i < cnt; i += blockDim.x) {
        unsigned key = (unsigned)bucket_ev[base + i].x;
        atomicAdd(&cnt_r[key >> 18], 1);
    }
    __syncthreads();
    int v = (tid < RPB) ? cnt_r[tid] : 0;
    s[tid] = v;
    __syncthreads();
    for (int off = 1; off < 256; off <<= 1) {
        int t = (tid >= off) ? s[tid - off] : 0;
        __syncthreads();
        s[tid] += t;
        __syncthreads();
    }
    if (tid < RPB) {
        int excl = cb + s[tid] - v;
        cur[tid] = excl;
        int r = row0 + tid;
        if (r < N_NODES) row_ptr[r] = excl;
    }
    __syncthreads();
    for (int i = tid; i < cnt; i += blockDim.x) {
        int2 ev = bucket_ev[base + i];
        unsigned key = (unsigned)ev.x;
        int rl  = (int)(key >> 18);
        int col = (int)(key & 0x3FFFFu);
        int pos = atomicAdd(&cur[rl], 1);
        int2 o; o.x = col; o.y = ev.y;
        csr_ev[pos] = o;
    }
}

// ---------------------------------------------------------------------------
// 6. CSR SpMM + fused emb_sum update. Half-wave per row, lane = dim.
// ---------------------------------------------------------------------------
__global__ void spmm_kernel(const int* __restrict__ row_ptr,
                            const int2* __restrict__ csr_ev,
                            const float* __restrict__ xin,
                            float* __restrict__ xout,
                            float* __restrict__ emb_sum) {
    int tid = blockIdx.x * blockDim.x + threadIdx.x;
    int row = tid >> 5;
    int d   = tid & 31;
    if (row >= N_NODES) return;
    int s = row_ptr[row];
    int e = row_ptr[row + 1];
    float acc = 0.f;
    int i = s;
    for (; i + 4 <= e; i += 4) {
        int2 e0 = csr_ev[i],     e1 = csr_ev[i + 1];
        int2 e2 = csr_ev[i + 2], e3 = csr_ev[i + 3];
        float x0 = xin[e0.x * DIM + d];
        float x1 = xin[e1.x * DIM + d];
        float x2 = xin[e2.x * DIM + d];
        float x3 = xin[e3.x * DIM + d];
        acc += __int_as_float(e0.y) * x0 + __int_as_float(e1.y) * x1
             + __int_as_float(e2.y) * x2 + __int_as_float(e3.y) * x3;
    }
    for (; i < e; ++i) {
        int2 ev = csr_ev[i];
        acc += __int_as_float(ev.y) * xin[ev.x * DIM + d];
    }
    int o = row * DIM + d;
    xout[o] = acc;
    emb_sum[o] += acc;
}

// ---------------------------------------------------------------------------
// 7. Readout.
// ---------------------------------------------------------------------------
__global__ void final_kernel(const int* __restrict__ users,
                             const int* __restrict__ items,
                             const float* __restrict__ emb_sum,
                             const float* __restrict__ means,
                             const float* __restrict__ stds,
                             float* __restrict__ out) {
    int b = blockIdx.x * blockDim.x + threadIdx.x;
    if (b >= B_OUT) return;
    int u  = users[b];
    int it = items[b] + N_USERS;
    const float4* su = (const float4*)(emb_sum + (size_t)u  * DIM);
    const float4* si = (const float4*)(emb_sum + (size_t)it * DIM);
    float gamma = 0.f;
    #pragma unroll
    for (int k = 0; k < DIM / 4; ++k) {
        float4 a = su[k], c = si[k];
        gamma += (a.x * 0.25f) * (c.x * 0.25f) + (a.y * 0.25f) * (c.y * 0.25f)
               + (a.z * 0.25f) * (c.z * 0.25f) + (a.w * 0.25f) * (c.w * 0.25f);
    }
    out[b] = gamma * stds[u] + means[u];
}

extern "C" void kernel_launch(void* const* d_in, const int* in_sizes, int n_in,
                              void* d_out, int out_size, void* d_ws, size_t ws_size,
                              hipStream_t stream) {
    const int*   users    = (const int*)d_in[0];
    const int*   items    = (const int*)d_in[1];
    const int*   rows     = (const int*)d_in[2];
    const int*   cols     = (const int*)d_in[3];
    const float* vals     = (const float*)d_in[4];
    const float* user_emb = (const float*)d_in[5];
    const float* item_emb = (const float*)d_in[6];
    const float* means    = (const float*)d_in[7];
    const float* stds     = (const float*)d_in[8];
    float* out = (float*)d_out;

    char* w = (char*)d_ws;
    size_t off = 0;
    auto alloc = [&](size_t bytes) -> void* {
        void* p = w + off;
        off = (off + bytes + 255) & ~(size_t)255;
        return p;
    };
    // Region A: bucket_ev (live: part -> mini_scatter) aliases
    //           {x_a, x_b, emb_sum} (live: init -> end).
    const size_t BEV_EDGES = (size_t)N_EDGES + NB * 8;   // padded
    size_t regionA = ((size_t)BEV_EDGES * sizeof(int2) + 255) & ~(size_t)255;
    char* a0 = (char*)alloc(regionA);
    int2* bucket_ev = (int2*)a0;
    size_t aoff = 0;
    auto allocA = [&](size_t bytes) -> void* {
        void* p = a0 + aoff;
        aoff = (aoff + bytes + 255) & ~(size_t)255;
        return p;
    };
    float* x_a     = (float*)allocA((size_t)N_NODES * DIM * sizeof(float));
    float* x_b     = (float*)allocA((size_t)N_NODES * DIM * sizeof(float));
    float* emb_sum = (float*)allocA((size_t)N_NODES * DIM * sizeof(float));
    // (aoff ~57.6MB <= regionA ~61.1MB)

    int*   row_ptr = (int*)  alloc((size_t)(N_NODES + 1) * sizeof(int));
    int*   bbase   = (int*)  alloc((size_t)NB * sizeof(int));
    int*   total   = (int*)  alloc((size_t)NB * sizeof(int));
    int*   gcur    = (int*)  alloc((size_t)NB * sizeof(int));
    int*   bcsr    = (int*)  alloc((size_t)NB * sizeof(int));
    int*   cntmat  = (int*)  alloc((size_t)N_PBLK * NB * sizeof(int));
    int2*  csr_ev  = (int2*) alloc((size_t)N_EDGES * sizeof(int2));
    (void)ws_size;

    const int T = 256;
    const int g_init  = (N_NODES * DIM / 4 + T - 1) / T;
    const int g_spmm  = (N_NODES * DIM + T - 1) / T;
    const int g_final = (B_OUT + T - 1) / T;

    // --- CSR build (no global atomics on hot paths) ---
    count_kernel<<<N_PBLK, PART_T, 0, stream>>>(rows, cntmat);
    reduce_kernel<<<NB / 16, 256, 0, stream>>>(cntmat, total);
    scan_buckets_kernel<<<1, NB, 0, stream>>>(total, bbase, gcur, bcsr, row_ptr);
    part_kernel<<<N_PBLK, PART_T, 0, stream>>>(rows, cols, vals, gcur, bucket_ev);
    mini_scatter_kernel<<<NB, T, 0, stream>>>(bucket_ev, bbase, total, bcsr, row_ptr, csr_ev);

    // --- dense pipeline (bucket_ev dead from here; region reused) ---
    init_kernel<<<g_init, T, 0, stream>>>(user_emb, item_emb, x_a, emb_sum);
    spmm_kernel<<<g_spmm, T, 0, stream>>>(row_ptr, csr_ev, x_a, x_b, emb_sum);
    spmm_kernel<<<g_spmm, T, 0, stream>>>(row_ptr, csr_ev, x_b, x_a, emb_sum);
    spmm_kernel<<<g_spmm, T, 0, stream>>>(row_ptr, csr_ev, x_a, x_b, emb_sum);

    final_kernel<<<g_final, T, 0, stream>>>(users, items, emb_sum, means, stds, out);
}